// Round 5
// baseline (421.714 us; speedup 1.0000x reference)
//
#include <hip/hip_runtime.h>

#define EMBED_D  2048
#define N_EXP    64
#define K_TOP    8
#define TOK_BLK  64
#define THREADS  256
#define NCHUNK   64             // K chunks of 32
#define WCHUNK_B 12288          // W frag bytes/chunk: 3 planes * 4 n * 64 lanes * 16
#define XCHUNK_B 8192           // X bytes/chunk: 64 tok * 32 k * 4
#define BUF_B    (WCHUNK_B + XCHUNK_B)   // 20480
#define NBUF     3

typedef __attribute__((ext_vector_type(8))) short bf16x8;   // 8 bf16 = 4 VGPR
typedef __attribute__((ext_vector_type(4))) float f32x4;    // MFMA C/D

__device__ __forceinline__ uint bf16_rne(float x) {
    uint u = __float_as_uint(x);
    return (u + 0x7fffu + ((u >> 16) & 1u)) >> 16;
}
__device__ __forceinline__ float bf16f(uint h) { return __uint_as_float(h << 16); }

// direct global->LDS, 16 B per lane; LDS dest = wave-uniform base + lane*16
__device__ __forceinline__ void stage16(const void* g, void* l)
{
    typedef __attribute__((address_space(1))) const unsigned int gu32;
    typedef __attribute__((address_space(3))) unsigned int lu32;
    __builtin_amdgcn_global_load_lds((gu32*)g, (lu32*)l, 16, 0, 0);
}

// x[8] -> h/m/l bf16x8. h,m: RNE; l: trunc. Identical to R4 -> same logits.
__device__ __forceinline__ void split3(float4 u, float4 v, bf16x8& H, bf16x8& M, bf16x8& L)
{
    const float x[8] = {u.x, u.y, u.z, u.w, v.x, v.y, v.z, v.w};
    uint hw[8], mw[8], lw[8];
#pragma unroll
    for (int j = 0; j < 8; ++j) {
        const uint ux = __float_as_uint(x[j]);
        hw[j] = (ux + 0x7fffu + ((ux >> 16) & 1u)) & 0xffff0000u;   // RNE, low16 zero
        const float r1 = x[j] - __uint_as_float(hw[j]);             // exact
        const uint ur = __float_as_uint(r1);
        mw[j] = (ur + 0x7fffu + ((ur >> 16) & 1u)) & 0xffff0000u;   // RNE
        lw[j] = __float_as_uint(r1 - __uint_as_float(mw[j]));       // trunc via pack
    }
    uint* hp = (uint*)&H; uint* mp = (uint*)&M; uint* lp = (uint*)&L;
#pragma unroll
    for (int w = 0; w < 4; ++w) {
        hp[w] = __builtin_amdgcn_perm(hw[2 * w + 1], hw[2 * w], 0x07060302u);
        mp[w] = __builtin_amdgcn_perm(mw[2 * w + 1], mw[2 * w], 0x07060302u);
        lp[w] = __builtin_amdgcn_perm(lw[2 * w + 1], lw[2 * w], 0x07060302u);
    }
}

// W[64][2048] fp32 -> fragment-major h/m/l planes, K32-chunk layout (same as R4).
// ushort offs: c*6144 + p*2048 + n*512 + lane*8;  e = n*16+row, k = c*32+g*8+j.
__global__ void w_prep(const float* __restrict__ W, ushort* __restrict__ WF)
{
    const int e = blockIdx.x;
    const int t = threadIdx.x;
    const float4 a = *(const float4*)(W + (size_t)e * EMBED_D + t * 8);
    const float4 b = *(const float4*)(W + (size_t)e * EMBED_D + t * 8 + 4);
    const float ev[8] = {a.x, a.y, a.z, a.w, b.x, b.y, b.z, b.w};
    ushort h[8], m[8], l[8];
#pragma unroll
    for (int j = 0; j < 8; ++j) {
        const uint hh = bf16_rne(ev[j]);
        const float r1 = ev[j] - bf16f(hh);
        const uint mm = bf16_rne(r1);
        const uint ll = bf16_rne(r1 - bf16f(mm));
        h[j] = (ushort)hh; m[j] = (ushort)mm; l[j] = (ushort)ll;
    }
    const int c = t >> 2;
    const int g = t & 3;
    const int lane = g * 16 + (e & 15);
    const int n    = e >> 4;
    const size_t base = (size_t)c * 6144 + (size_t)n * 512 + (size_t)lane * 8;
    ushort4* H = (ushort4*)(WF + base);
    ushort4* M = (ushort4*)(WF + base + 2048);
    ushort4* L = (ushort4*)(WF + base + 4096);
    H[0] = make_ushort4(h[0], h[1], h[2], h[3]); H[1] = make_ushort4(h[4], h[5], h[6], h[7]);
    M[0] = make_ushort4(m[0], m[1], m[2], m[3]); M[1] = make_ushort4(m[4], m[5], m[6], m[7]);
    L[0] = make_ushort4(l[0], l[1], l[2], l[3]); L[1] = make_ushort4(l[4], l[5], l[6], l[7]);
}

__global__ __launch_bounds__(THREADS, 2) void moe_gate_main(
    const float*  __restrict__ X,    // [n_tok][2048] fp32
    const ushort* __restrict__ WF,   // fragment-major W planes (768 KB)
    float* __restrict__ out,
    float* __restrict__ ws,
    int n_tok)
{
    // 3 pipeline buffers {W 12K | X 8K}; reused as Lp after the loop. 60 KB.
    __shared__ __align__(16) char smem[NBUF * BUF_B];
    __shared__ float sInvZ[TOK_BLK];
    __shared__ float sCnt[N_EXP];
    __shared__ float sColp[4][N_EXP];

    const int tid  = threadIdx.x;
    const int lane = tid & 63;
    const int wv   = __builtin_amdgcn_readfirstlane(tid >> 6);  // 0..3
    const int row  = lane & 15;
    const int g    = lane >> 4;
    const int t0   = blockIdx.x * TOK_BLK;

    // ---- staging addresses ----
    // W: op r in 0..2 -> dest buf + (r*4+wv)*1024, src WF + c*12288 + same + lane*16
    const char* wsrc = (const char*)WF + (size_t)(wv * 1024) + lane * 16;
    // X: wave w region = 2 KB (its 16 tokens). op i in 0..1, slot s = i*64+lane:
    //   lt = s>>1, c0 = (lt>>2)&1, r = (s&1)^c0, gg = lt>>4, rr = lt&15
    //   src = X[(t0 + wv*16 + rr)][c*32 + gg*8 + r*4]
    const float* xsrc[2];
    {
#pragma unroll
        for (int i = 0; i < 2; ++i) {
            const int s  = i * 64 + lane;
            const int lt = s >> 1;
            const int r  = (s & 1) ^ ((lt >> 2) & 1);
            const int gg = lt >> 4, rr = lt & 15;
            xsrc[i] = X + (size_t)(t0 + wv * 16 + rr) * EMBED_D + gg * 8 + r * 4;
        }
    }
    // X read slots (bank-bijective): s0 = 2*lane + c0, s1 = 2*lane + (c0^1)
    const int c0  = (lane >> 2) & 1;
    const int xo0 = (2 * lane + c0) * 16;
    const int xo1 = (2 * lane + (c0 ^ 1)) * 16;

    f32x4 acc[4];
#pragma unroll
    for (int n = 0; n < 4; ++n) acc[n] = (f32x4){0.f, 0.f, 0.f, 0.f};

    // ---- prologue: stage chunks 0,1 into slots 0,1 (5 loads each per wave) ----
#pragma unroll
    for (int c = 0; c < 2; ++c) {
        char* bb = smem + c * BUF_B;
#pragma unroll
        for (int r = 0; r < 3; ++r)
            stage16(wsrc + (size_t)c * WCHUNK_B + r * 4096, bb + (r * 4 + wv) * 1024);
#pragma unroll
        for (int i = 0; i < 2; ++i)
            stage16(xsrc[i] + c * 32, bb + WCHUNK_B + wv * 2048 + i * 1024);
    }

    for (int c = 0; c < NCHUNK; ++c) {
        // (1) counted wait: stage c complete (stage c+1 = 5 ops may stay in flight)
        if (c + 1 < NCHUNK) asm volatile("s_waitcnt vmcnt(5)" ::: "memory");
        else                asm volatile("s_waitcnt vmcnt(0)" ::: "memory");
        __builtin_amdgcn_sched_barrier(0);
        __builtin_amdgcn_s_barrier();    // all waves: buffer c ready, slot c-1 free

        // (2) issue stage c+2 into slot (c+2)%3 == slot of c-1 (fire and forget)
        if (c + 2 < NCHUNK) {
            char* bb = smem + ((c + 2) % NBUF) * BUF_B;
#pragma unroll
            for (int r = 0; r < 3; ++r)
                stage16(wsrc + (size_t)(c + 2) * WCHUNK_B + r * 4096, bb + (r * 4 + wv) * 1024);
#pragma unroll
            for (int i = 0; i < 2; ++i)
                stage16(xsrc[i] + (c + 2) * 32, bb + WCHUNK_B + wv * 2048 + i * 1024);
        }

        // (3) compute chunk c
        const char* bb = smem + (c % NBUF) * BUF_B;
        const char* xb = bb + WCHUNK_B + wv * 2048;

        bf16x8 ah, am, al;
        {
            const float4 u = *(const float4*)(xb + xo0);   // k g*8+0..3
            const float4 v = *(const float4*)(xb + xo1);   // k g*8+4..7
            split3(u, v, ah, am, al);
        }
#pragma unroll
        for (int n = 0; n < 4; ++n) {
            const char* bp = bb + n * 1024 + lane * 16;
            const bf16x8 bh = *(const bf16x8*)(bp);
            const bf16x8 bm = *(const bf16x8*)(bp + 4096);
            const bf16x8 bl = *(const bf16x8*)(bp + 8192);
            acc[n] = __builtin_amdgcn_mfma_f32_16x16x32_bf16(ah, bh, acc[n], 0, 0, 0);
            acc[n] = __builtin_amdgcn_mfma_f32_16x16x32_bf16(am, bh, acc[n], 0, 0, 0);
            acc[n] = __builtin_amdgcn_mfma_f32_16x16x32_bf16(ah, bm, acc[n], 0, 0, 0);
            acc[n] = __builtin_amdgcn_mfma_f32_16x16x32_bf16(al, bh, acc[n], 0, 0, 0);
            acc[n] = __builtin_amdgcn_mfma_f32_16x16x32_bf16(ah, bl, acc[n], 0, 0, 0);
            acc[n] = __builtin_amdgcn_mfma_f32_16x16x32_bf16(am, bm, acc[n], 0, 0, 0);
        }
    }
    __syncthreads();   // all waves done computing -> buffers reusable as Lp

    // reuse smem as logits [tok][exp], stride 65
    float (*Lp)[N_EXP + 1] = (float (*)[N_EXP + 1])smem;
    // C/D layout: token = wv*16 + g*4 + reg, expert = n*16 + (lane&15)
#pragma unroll
    for (int n = 0; n < 4; ++n)
#pragma unroll
        for (int r = 0; r < 4; ++r)
            Lp[wv * 16 + g * 4 + r][n * 16 + row] = acc[n][r];
    if (tid < N_EXP) sCnt[tid] = 0.f;
    __syncthreads();

    // per-token softmax + top-8 (threads 0..63)
    if (tid < TOK_BLK) {
        const int t = tid;
        float mx = -1e30f;
        for (int e = 0; e < N_EXP; ++e)
            mx = fmaxf(mx, Lp[t][e]);
        float Z = 0.f;
        float tv[K_TOP]; int ti[K_TOP];
#pragma unroll
        for (int j = 0; j < K_TOP; ++j) { tv[j] = -1e30f; ti[j] = 0; }
        for (int e = 0; e < N_EXP; ++e) {
            const float s = __expf(Lp[t][e] - mx);
            Lp[t][e] = s;                 // unnormalized score for Pi pass
            Z += s;
            float v = s; int id = e;
#pragma unroll
            for (int j = 0; j < K_TOP; ++j) {  // strict > : ties keep lower idx
                if (v > tv[j]) {
                    float fv = tv[j]; tv[j] = v; v = fv;
                    int   fi = ti[j]; ti[j] = id; id = fi;
                }
            }
        }
        const float invZ = 1.0f / Z;
        sInvZ[t] = invZ;
        const size_t ob = (size_t)(t0 + t) * K_TOP;
        const size_t wo = (size_t)n_tok * K_TOP;
#pragma unroll
        for (int j = 0; j < K_TOP; ++j) {
            out[ob + j]      = (float)ti[j];
            out[wo + ob + j] = tv[j] * invZ;
            atomicAdd(&sCnt[ti[j]], 1.0f);
        }
    }
    __syncthreads();

    // per-expert score sums (Pi numerator): 4 groups x 16 tokens
    {
        const int e = tid & 63, g2 = tid >> 6;
        float s = 0.f;
#pragma unroll
        for (int i = 0; i < 16; ++i) {
            const int t = g2 * 16 + i;
            s += Lp[t][e] * sInvZ[t];
        }
        sColp[g2][e] = s;
    }
    __syncthreads();
    if (tid < N_EXP) {
        float s = 0.f;
#pragma unroll
        for (int g2 = 0; g2 < 4; ++g2) s += sColp[g2][tid];
        atomicAdd(&ws[64 + tid], s);
        atomicAdd(&ws[tid], sCnt[tid]);
    }
}

__global__ void moe_aux(const float* __restrict__ ws, float* __restrict__ out, int n_tok)
{
    const int e = threadIdx.x;   // 64 threads
    const float counts = ws[e];
    const float ssum   = ws[64 + e];
    const float Pi = ssum / (float)n_tok;
    const float ce = counts / ((float)n_tok * (float)K_TOP);
    float term = Pi * ce * (float)N_EXP;
    for (int off = 32; off; off >>= 1) term += __shfl_down(term, off);
    if (e == 0) out[(size_t)2 * n_tok * K_TOP] = term * 0.01f;
}

extern "C" void kernel_launch(void* const* d_in, const int* in_sizes, int n_in,
                              void* d_out, int out_size, void* d_ws, size_t ws_size,
                              hipStream_t stream)
{
    const float* X = (const float*)d_in[0];
    const float* W = (const float*)d_in[1];
    float* out = (float*)d_out;
    float* ws  = (float*)d_ws;
    const int n_tok = in_sizes[0] / EMBED_D;   // 32768

    // workspace: [0..255] floats counters | fragment-major W planes (768 KB)
    ushort* WF = (ushort*)(ws + 256);

    hipMemsetAsync(ws, 0, 2 * N_EXP * sizeof(float), stream);
    w_prep<<<N_EXP, 256, 0, stream>>>(W, WF);
    moe_gate_main<<<n_tok / TOK_BLK, THREADS, 0, stream>>>(X, WF, out, ws, n_tok);
    moe_aux<<<1, 64, 0, stream>>>(ws, out, n_tok);
}

// Round 6
// 411.273 us; speedup vs baseline: 1.0254x; 1.0254x over previous
//
#include <hip/hip_runtime.h>

#define EMBED_D  2048
#define N_EXP    64
#define K_TOP    8
#define TOK_BLK  128
#define THREADS  512            // 8 waves x 16 tokens, all 64 experts each
#define NCHUNK   32             // K chunks of 64
#define WCHUNK_B 24576          // W frag bytes per K64 chunk (2 x K32 sub-blocks)
#define NBUF     3

typedef __attribute__((ext_vector_type(8))) short bf16x8;   // 8 bf16 = 4 VGPR
typedef __attribute__((ext_vector_type(4))) float f32x4;    // MFMA C/D

__device__ __forceinline__ uint bf16_rne(float x) {
    uint u = __float_as_uint(x);
    return (u + 0x7fffu + ((u >> 16) & 1u)) >> 16;
}
__device__ __forceinline__ float bf16f(uint h) { return __uint_as_float(h << 16); }

// direct global->LDS, 16 B per lane; LDS dest = wave-uniform base + lane*16
__device__ __forceinline__ void stage16(const void* g, void* l)
{
    typedef __attribute__((address_space(1))) const unsigned int gu32;
    typedef __attribute__((address_space(3))) unsigned int lu32;
    __builtin_amdgcn_global_load_lds((gu32*)g, (lu32*)l, 16, 0, 0);
}

// x[8] -> h/m/l bf16x8. h,m: RNE; l: trunc. Identical to R4/R5 -> same logits.
__device__ __forceinline__ void split3(float4 u, float4 v, bf16x8& H, bf16x8& M, bf16x8& L)
{
    const float x[8] = {u.x, u.y, u.z, u.w, v.x, v.y, v.z, v.w};
    uint hw[8], mw[8], lw[8];
#pragma unroll
    for (int j = 0; j < 8; ++j) {
        const uint ux = __float_as_uint(x[j]);
        hw[j] = (ux + 0x7fffu + ((ux >> 16) & 1u)) & 0xffff0000u;   // RNE, low16 zero
        const float r1 = x[j] - __uint_as_float(hw[j]);             // exact
        const uint ur = __float_as_uint(r1);
        mw[j] = (ur + 0x7fffu + ((ur >> 16) & 1u)) & 0xffff0000u;   // RNE
        lw[j] = __float_as_uint(r1 - __uint_as_float(mw[j]));       // trunc via pack
    }
    uint* hp = (uint*)&H; uint* mp = (uint*)&M; uint* lp = (uint*)&L;
#pragma unroll
    for (int w = 0; w < 4; ++w) {
        hp[w] = __builtin_amdgcn_perm(hw[2 * w + 1], hw[2 * w], 0x07060302u);
        mp[w] = __builtin_amdgcn_perm(mw[2 * w + 1], mw[2 * w], 0x07060302u);
        lp[w] = __builtin_amdgcn_perm(lw[2 * w + 1], lw[2 * w], 0x07060302u);
    }
}

// W[64][2048] fp32 -> fragment-major h/m/l planes, K32-sub-block layout (as R5).
// Byte offs: c32*12288 + p*4096 + n*1024 + lane*16; e = n*16+row, k = c32*32+g*8+j,
// lane = g*16+row. A K64 chunk c = two consecutive K32 blocks = contiguous 24 KB.
__global__ void w_prep(const float* __restrict__ W, ushort* __restrict__ WF)
{
    const int e = blockIdx.x;
    const int t = threadIdx.x;
    const float4 a = *(const float4*)(W + (size_t)e * EMBED_D + t * 8);
    const float4 b = *(const float4*)(W + (size_t)e * EMBED_D + t * 8 + 4);
    const float ev[8] = {a.x, a.y, a.z, a.w, b.x, b.y, b.z, b.w};
    ushort h[8], m[8], l[8];
#pragma unroll
    for (int j = 0; j < 8; ++j) {
        const uint hh = bf16_rne(ev[j]);
        const float r1 = ev[j] - bf16f(hh);
        const uint mm = bf16_rne(r1);
        const uint ll = bf16_rne(r1 - bf16f(mm));
        h[j] = (ushort)hh; m[j] = (ushort)mm; l[j] = (ushort)ll;
    }
    const int c = t >> 2;           // K32 sub-block
    const int g = t & 3;
    const int lane = g * 16 + (e & 15);
    const int n    = e >> 4;
    const size_t base = (size_t)c * 6144 + (size_t)n * 512 + (size_t)lane * 8;  // ushorts
    ushort4* H = (ushort4*)(WF + base);
    ushort4* M = (ushort4*)(WF + base + 2048);
    ushort4* L = (ushort4*)(WF + base + 4096);
    H[0] = make_ushort4(h[0], h[1], h[2], h[3]); H[1] = make_ushort4(h[4], h[5], h[6], h[7]);
    M[0] = make_ushort4(m[0], m[1], m[2], m[3]); M[1] = make_ushort4(m[4], m[5], m[6], m[7]);
    L[0] = make_ushort4(l[0], l[1], l[2], l[3]); L[1] = make_ushort4(l[4], l[5], l[6], l[7]);
}

__global__ __launch_bounds__(THREADS, 2) void moe_gate_main(
    const float*  __restrict__ X,    // [n_tok][2048] fp32
    const ushort* __restrict__ WF,   // fragment-major W planes (768 KB)
    float* __restrict__ out,
    float* __restrict__ ws,
    int n_tok)
{
    // 3 W pipeline slots (72 KB); reused as Lp[128][65] after the loop.
    __shared__ __align__(16) char smem[NBUF * WCHUNK_B];
    __shared__ float sInvZ[TOK_BLK];
    __shared__ float sCnt[N_EXP];
    __shared__ float sColp[8][N_EXP];

    const int tid  = threadIdx.x;
    const int lane = tid & 63;
    const int wv   = __builtin_amdgcn_readfirstlane(tid >> 6);  // 0..7
    const int row  = lane & 15;
    const int g    = lane >> 4;
    const int t0   = blockIdx.x * TOK_BLK;

    // X: straight to registers. lane holds token (wv*16+row), k-group g.
    const float* xbase = X + (size_t)(t0 + wv * 16 + row) * EMBED_D + (g << 3);
    // W staging source: this wave's 3 x 1KB pieces per chunk.
    const char* wsrc = (const char*)WF + (size_t)(wv * 1024) + lane * 16;

    f32x4 acc[4];
#pragma unroll
    for (int n = 0; n < 4; ++n) acc[n] = (f32x4){0.f, 0.f, 0.f, 0.f};

    float4 xA[4], xB[4];

    // ---- prologue: batch0 (X0 4 + W0 3), fence, batch1 (X1 4 + W1 3) ----
    xA[0] = *(const float4*)(xbase);
    xA[1] = *(const float4*)(xbase + 4);
    xA[2] = *(const float4*)(xbase + 32);
    xA[3] = *(const float4*)(xbase + 36);
#pragma unroll
    for (int r = 0; r < 3; ++r)
        stage16(wsrc + r * 8192, smem + wv * 1024 + r * 8192);
    __builtin_amdgcn_sched_barrier(0);
    xB[0] = *(const float4*)(xbase + 64);
    xB[1] = *(const float4*)(xbase + 68);
    xB[2] = *(const float4*)(xbase + 96);
    xB[3] = *(const float4*)(xbase + 100);
#pragma unroll
    for (int r = 0; r < 3; ++r)
        stage16(wsrc + WCHUNK_B + r * 8192, smem + WCHUNK_B + wv * 1024 + r * 8192);
    __builtin_amdgcn_sched_barrier(0);

    int s_cur = 0;   // LDS slot of the current chunk

#define BODY(C, XQ)                                                              \
    {                                                                            \
        __builtin_amdgcn_sched_barrier(0);                                       \
        if ((C) + 1 < NCHUNK) asm volatile("s_waitcnt vmcnt(7)" ::: "memory");   \
        else                  asm volatile("s_waitcnt vmcnt(0)" ::: "memory");   \
        __builtin_amdgcn_sched_barrier(0);                                       \
        __builtin_amdgcn_s_barrier();                                            \
        __builtin_amdgcn_sched_barrier(0);                                       \
        const char* bb = smem + s_cur * WCHUNK_B;                                \
        _Pragma("unroll")                                                        \
        for (int kk = 0; kk < 2; ++kk) {                                         \
            bf16x8 ah, am, al;                                                   \
            split3(XQ[2 * kk], XQ[2 * kk + 1], ah, am, al);                      \
            _Pragma("unroll")                                                    \
            for (int n = 0; n < 4; ++n) {                                        \
                const char* bp = bb + kk * 12288 + n * 1024 + (lane << 4);       \
                const bf16x8 bh = *(const bf16x8*)(bp);                          \
                const bf16x8 bm = *(const bf16x8*)(bp + 4096);                   \
                const bf16x8 bl = *(const bf16x8*)(bp + 8192);                   \
                acc[n] = __builtin_amdgcn_mfma_f32_16x16x32_bf16(ah, bh, acc[n], 0, 0, 0); \
                acc[n] = __builtin_amdgcn_mfma_f32_16x16x32_bf16(am, bh, acc[n], 0, 0, 0); \
                acc[n] = __builtin_amdgcn_mfma_f32_16x16x32_bf16(ah, bm, acc[n], 0, 0, 0); \
                acc[n] = __builtin_amdgcn_mfma_f32_16x16x32_bf16(al, bh, acc[n], 0, 0, 0); \
                acc[n] = __builtin_amdgcn_mfma_f32_16x16x32_bf16(ah, bl, acc[n], 0, 0, 0); \
                acc[n] = __builtin_amdgcn_mfma_f32_16x16x32_bf16(am, bm, acc[n], 0, 0, 0); \
            }                                                                    \
        }                                                                        \
        __builtin_amdgcn_sched_barrier(0);                                       \
        if ((C) + 2 < NCHUNK) {                                                  \
            const float* xs = xbase + ((C) + 2) * 64;                            \
            XQ[0] = *(const float4*)(xs);                                        \
            XQ[1] = *(const float4*)(xs + 4);                                    \
            XQ[2] = *(const float4*)(xs + 32);                                   \
            XQ[3] = *(const float4*)(xs + 36);                                   \
            const int s2 = (s_cur + 2 >= NBUF) ? s_cur - 1 : s_cur + 2;          \
            char* db = smem + s2 * WCHUNK_B + wv * 1024;                         \
            const char* gw = wsrc + (size_t)((C) + 2) * WCHUNK_B;                \
            stage16(gw,         db);                                             \
            stage16(gw + 8192,  db + 8192);                                      \
            stage16(gw + 16384, db + 16384);                                     \
        }                                                                        \
        __builtin_amdgcn_sched_barrier(0);                                       \
        s_cur = (s_cur == NBUF - 1) ? 0 : s_cur + 1;                             \
    }

    for (int c = 0; c < NCHUNK; c += 2) {
        BODY(c, xA)
        BODY(c + 1, xB)
    }
#undef BODY

    __syncthreads();   // all waves done -> W slots reusable as Lp

    // reuse smem as logits [tok][exp], stride 65 (33280 B <= 73728 B)
    float (*Lp)[N_EXP + 1] = (float (*)[N_EXP + 1])smem;
    // C/D layout: token = wv*16 + g*4 + reg, expert = n*16 + (lane&15)
#pragma unroll
    for (int n = 0; n < 4; ++n)
#pragma unroll
        for (int r = 0; r < 4; ++r)
            Lp[wv * 16 + g * 4 + r][n * 16 + row] = acc[n][r];
    if (tid < N_EXP) sCnt[tid] = 0.f;
    __syncthreads();

    // per-token softmax + top-8 (threads 0..127 = waves 0,1)
    if (tid < TOK_BLK) {
        const int t = tid;
        float mx = -1e30f;
        for (int e = 0; e < N_EXP; ++e)
            mx = fmaxf(mx, Lp[t][e]);
        float Z = 0.f;
        float tv[K_TOP]; int ti[K_TOP];
#pragma unroll
        for (int j = 0; j < K_TOP; ++j) { tv[j] = -1e30f; ti[j] = 0; }
        for (int e = 0; e < N_EXP; ++e) {
            const float s = __expf(Lp[t][e] - mx);
            Lp[t][e] = s;                 // unnormalized score for Pi pass
            Z += s;
            float v = s; int id = e;
#pragma unroll
            for (int j = 0; j < K_TOP; ++j) {  // strict > : ties keep lower idx
                if (v > tv[j]) {
                    float fv = tv[j]; tv[j] = v; v = fv;
                    int   fi = ti[j]; ti[j] = id; id = fi;
                }
            }
        }
        const float invZ = 1.0f / Z;
        sInvZ[t] = invZ;
        const size_t ob = (size_t)(t0 + t) * K_TOP;
        const size_t wo = (size_t)n_tok * K_TOP;
#pragma unroll
        for (int j = 0; j < K_TOP; ++j) {
            out[ob + j]      = (float)ti[j];
            out[wo + ob + j] = tv[j] * invZ;
            atomicAdd(&sCnt[ti[j]], 1.0f);
        }
    }
    __syncthreads();

    // per-expert score sums (Pi numerator): 8 groups x 16 tokens
    {
        const int e = tid & 63, g2 = tid >> 6;
        float s = 0.f;
#pragma unroll
        for (int i = 0; i < 16; ++i) {
            const int t = g2 * 16 + i;
            s += Lp[t][e] * sInvZ[t];
        }
        sColp[g2][e] = s;
    }
    __syncthreads();
    if (tid < N_EXP) {
        float s = 0.f;
#pragma unroll
        for (int g2 = 0; g2 < 8; ++g2) s += sColp[g2][tid];
        atomicAdd(&ws[64 + tid], s);
        atomicAdd(&ws[tid], sCnt[tid]);
    }
}

__global__ void moe_aux(const float* __restrict__ ws, float* __restrict__ out, int n_tok)
{
    const int e = threadIdx.x;   // 64 threads
    const float counts = ws[e];
    const float ssum   = ws[64 + e];
    const float Pi = ssum / (float)n_tok;
    const float ce = counts / ((float)n_tok * (float)K_TOP);
    float term = Pi * ce * (float)N_EXP;
    for (int off = 32; off; off >>= 1) term += __shfl_down(term, off);
    if (e == 0) out[(size_t)2 * n_tok * K_TOP] = term * 0.01f;
}

extern "C" void kernel_launch(void* const* d_in, const int* in_sizes, int n_in,
                              void* d_out, int out_size, void* d_ws, size_t ws_size,
                              hipStream_t stream)
{
    const float* X = (const float*)d_in[0];
    const float* W = (const float*)d_in[1];
    float* out = (float*)d_out;
    float* ws  = (float*)d_ws;
    const int n_tok = in_sizes[0] / EMBED_D;   // 32768

    // workspace: [0..255] floats counters | fragment-major W planes (768 KB)
    ushort* WF = (ushort*)(ws + 256);

    hipMemsetAsync(ws, 0, 2 * N_EXP * sizeof(float), stream);
    w_prep<<<N_EXP, 256, 0, stream>>>(W, WF);
    moe_gate_main<<<n_tok / TOK_BLK, THREADS, 0, stream>>>(X, WF, out, ws, n_tok);
    moe_aux<<<1, 64, 0, stream>>>(ws, out, n_tok);
}